// Round 10
// baseline (248.405 us; speedup 1.0000x reference)
//
#include <hip/hip_runtime.h>

#define NN 50000
#define NE 400000

typedef unsigned short u16;
typedef unsigned int   u32;
typedef __bf16 bf16x4 __attribute__((ext_vector_type(4)));
typedef __bf16 bf16x8 __attribute__((ext_vector_type(8)));
typedef float  f32x4  __attribute__((ext_vector_type(4)));

union ABFrag { bf16x8 v; bf16x4 h[2]; };
union BFrag  { uint4 u; bf16x8 v; };

__device__ __forceinline__ u16 f2bfu(float f) {
  u32 u = __builtin_bit_cast(u32, f);
  return (u16)((u + 0x7FFFu + ((u >> 16) & 1u)) >> 16);  // RNE f32->bf16
}
__device__ __forceinline__ float bf2f(u16 u) {
  return __builtin_bit_cast(float, (u32)u << 16);
}

// ---------------- prep: cvt + weight-pack + hist in ONE launch ---------------
// pack[((t*256+n)*4+g)*8+j] = W[32t + 4g + (j%4) + 16*(j/4)][n]
__device__ __forceinline__ void pack_one(const float* __restrict__ W,
                                         u16* __restrict__ P, int idx) {
  int k = idx >> 8, n = idx & 255;
  int t = k >> 5, kp = k & 31;
  int g = (kp & 15) >> 2;
  int j = (kp & 3) | ((kp >> 4) << 2);
  P[(((t << 8) + n) << 5) + (g << 3) + j] = f2bfu(W[idx]);
}

#define NB_CVT  12500      // NN*256/4 / 256
#define NB_PACK 1088       // (320*256 + 3*256*256) / 256
#define NB_HIST 1563       // ceil(NE/256)

__global__ __launch_bounds__(256) void k_prep(
    const float* __restrict__ nodes, u16* __restrict__ nodes_bf,
    const float* __restrict__ Wm, const float* __restrict__ W0,
    const float* __restrict__ W1, const float* __restrict__ W2,
    u16* __restrict__ Pm, u16* __restrict__ P0,
    u16* __restrict__ P1, u16* __restrict__ P2,
    const int* __restrict__ recv, int* __restrict__ cnt)
{
  int b = blockIdx.x, t = threadIdx.x;
  if (b < NB_CVT) {
    int i = b * 256 + t;                         // exact: 12500*256 = NN*64
    float4 f = ((const float4*)nodes)[i];
    ushort4 o;
    o.x = f2bfu(f.x); o.y = f2bfu(f.y); o.z = f2bfu(f.z); o.w = f2bfu(f.w);
    ((ushort4*)nodes_bf)[i] = o;
  } else if (b < NB_CVT + NB_PACK) {
    int idx = (b - NB_CVT) * 256 + t;
    const int S0 = 320 * 256, S1 = S0 + 65536, S2 = S1 + 65536;
    if (idx < S0)      pack_one(Wm, Pm, idx);
    else if (idx < S1) pack_one(W0, P0, idx - S0);
    else if (idx < S2) pack_one(W1, P1, idx - S1);
    else               pack_one(W2, P2, idx - S2);
  } else {
    int i = (b - NB_CVT - NB_PACK) * 256 + t;
    if (i < NE) atomicAdd(&cnt[recv[i]], 1);
  }
}

// ---------------- counting-sort scan + scatter -------------------------------
__global__ __launch_bounds__(256) void k_scan1(const int* __restrict__ cnt,
                                               int* __restrict__ loc,
                                               int* __restrict__ bsum) {
  __shared__ int sm[256];
  int t = threadIdx.x, i = blockIdx.x * 256 + t;
  int v = (i < NN) ? cnt[i] : 0;
  sm[t] = v;
  __syncthreads();
  #pragma unroll
  for (int d = 1; d < 256; d <<= 1) {
    int x = sm[t];
    int y = (t >= d) ? sm[t - d] : 0;
    __syncthreads();
    sm[t] = x + y;
    __syncthreads();
  }
  if (i < NN) loc[i] = sm[t] - v;
  if (t == 255) bsum[blockIdx.x] = sm[255];
}

__global__ __launch_bounds__(256) void k_scan2(int* __restrict__ bsum,
                                               int* __restrict__ bpre, int nb) {
  __shared__ int sm[256];
  int t = threadIdx.x;
  int v = (t < nb) ? bsum[t] : 0;
  sm[t] = v;
  __syncthreads();
  #pragma unroll
  for (int d = 1; d < 256; d <<= 1) {
    int x = sm[t];
    int y = (t >= d) ? sm[t - d] : 0;
    __syncthreads();
    sm[t] = x + y;
    __syncthreads();
  }
  if (t < nb) bpre[t] = sm[t] - v;
}

__global__ __launch_bounds__(256) void k_scan3(const int* __restrict__ loc,
                                               const int* __restrict__ bpre,
                                               int* __restrict__ offs,
                                               int* __restrict__ cursor) {
  int i = blockIdx.x * 256 + threadIdx.x;
  if (i < NN) {
    int o = loc[i] + bpre[blockIdx.x];
    offs[i] = o;
    cursor[i] = o;
  }
  if (i == NN - 1) offs[NN] = NE;
}

__global__ __launch_bounds__(256) void k_scatter(
    const int* __restrict__ snd, const int* __restrict__ recv,
    int* __restrict__ cursor, int* __restrict__ s_snd, int* __restrict__ s_eid) {
  int e = blockIdx.x * 256 + threadIdx.x;
  if (e < NE) {
    int p = atomicAdd(&cursor[recv[e]], 1);
    s_snd[p] = snd[e];
    s_eid[p] = e;
  }
}

// ---------------- aggregation: software-pipelined flat edge stream -----------
// One wave per 4 consecutive nodes; their edges processed as one flat stream
// with a 2-stage x 4-wide batch pipeline: 8 independent loads (4 row-gathers
// + 4 edge rows) in flight while the previous batch is accumulated (VALU).
// Named registers only (no runtime-indexed arrays -> no scratch).
__global__ __launch_bounds__(256) void k_aggr(
    const u16* __restrict__ nodes_bf, const float* __restrict__ edges,
    const int* __restrict__ offs, const int* __restrict__ s_snd,
    const int* __restrict__ s_eid, u16* __restrict__ X)
{
  const int wid = blockIdx.x * 4 + (threadIdx.x >> 6);   // wave id (grid exact)
  const int lane = threadIdx.x & 63;
  const int n0 = wid * 4;                                 // 3125*16 = 50000 exact
  const int o0 = offs[n0], b1 = offs[n0 + 1], b2 = offs[n0 + 2],
            b3 = offs[n0 + 3], o4 = offs[n0 + 4];

  float a0 = 0.f, a1 = 0.f, a2 = 0.f, a3 = 0.f, a4 = 0.f;
  int cur = 0;

#define AGLD(J, NV, EV) do { int _j = (J); if (_j < o4) { \
    int _s = s_snd[_j], _e = s_eid[_j]; \
    NV = *(const ushort4*)(nodes_bf + (size_t)_s * 256 + (lane << 2)); \
    EV = edges[(size_t)_e * 64 + lane]; } } while (0)

#define AGFLUSH(NODE) do { \
    ushort4 _o; _o.x = f2bfu(a0); _o.y = f2bfu(a1); _o.z = f2bfu(a2); _o.w = f2bfu(a3); \
    u16* _xr = X + (size_t)(NODE) * 320; \
    *(ushort4*)(_xr + (lane << 2)) = _o; \
    _xr[256 + lane] = f2bfu(a4); \
    a0 = 0.f; a1 = 0.f; a2 = 0.f; a3 = 0.f; a4 = 0.f; } while (0)

#define AGCONS(J, NV, EV) do { int _j = (J); if (_j < o4) { \
    if (cur == 0 && _j == b1) { AGFLUSH(n0);     cur = 1; } \
    if (cur == 1 && _j == b2) { AGFLUSH(n0 + 1); cur = 2; } \
    if (cur == 2 && _j == b3) { AGFLUSH(n0 + 2); cur = 3; } \
    a0 += bf2f(NV.x); a1 += bf2f(NV.y); a2 += bf2f(NV.z); a3 += bf2f(NV.w); \
    a4 += EV; } } while (0)

  ushort4 v0 = {0,0,0,0}, v1 = {0,0,0,0}, v2 = {0,0,0,0}, v3 = {0,0,0,0};
  float e0 = 0.f, e1 = 0.f, e2 = 0.f, e3 = 0.f;
  AGLD(o0 + 0, v0, e0); AGLD(o0 + 1, v1, e1);
  AGLD(o0 + 2, v2, e2); AGLD(o0 + 3, v3, e3);

  for (int jb = o0; jb < o4; jb += 4) {
    ushort4 w0 = {0,0,0,0}, w1 = {0,0,0,0}, w2 = {0,0,0,0}, w3 = {0,0,0,0};
    float f0 = 0.f, f1 = 0.f, f2 = 0.f, f3 = 0.f;
    AGLD(jb + 4, w0, f0); AGLD(jb + 5, w1, f1);   // next batch in flight
    AGLD(jb + 6, w2, f2); AGLD(jb + 7, w3, f3);
    AGCONS(jb + 0, v0, e0); AGCONS(jb + 1, v1, e1);
    AGCONS(jb + 2, v2, e2); AGCONS(jb + 3, v3, e3);
    v0 = w0; v1 = w1; v2 = w2; v3 = w3;
    e0 = f0; e1 = f1; e2 = f2; e3 = f3;
  }
  for (int k = cur; k < 4; ++k) AGFLUSH(n0 + k);  // last node + trailing empties
#undef AGLD
#undef AGFLUSH
#undef AGCONS
}

// ---------------- fully fused dense chain ------------------------------------
// 1024 threads = 16 waves; per-wave tile 16x64; acc[4] = 16 VGPRs -> fits the
// allocator's 64-reg tier spill-free (R8-verified). Key R10 change: the B-tile
// prefetch is issued AFTER barrier#2, so hipcc's vmcnt(0)-drain-at-barrier
// lands at the NEXT step's barrier#1 -- covered by the whole MFMA phase.

#define AT_ADDR(r, c) (atb + ((((r) * 640) + ((c) * 2)) ^ (((r) & 7) << 4)))

#define WRBT(c, v) do { int _c = (c); \
  int _i = (((_c >> 10) << 13) + ((_c & 3) << 11) + (((_c & 1023) >> 2) << 3)) ^ ((_c & 3) << 4); \
  *(uint4*)&Bt[_i] = (v); } while (0)

#define MFMA_STEP(t) \
  _Pragma("unroll") \
  for (int kk = 0; kk < 2; ++kk) { \
    ABFrag a; \
    const int kc = (((t) * 2 + kk) << 5) + (g << 2); \
    const int m = wr16 + l16; \
    a.h[0] = *(const bf16x4*)AT_ADDR(m, kc); \
    a.h[1] = *(const bf16x4*)AT_ADDR(m, kc + 16); \
    _Pragma("unroll") \
    for (int q = 0; q < 4; ++q) { \
      BFrag b; \
      b.u = *(const uint4*)&Bt[((kk << 13) + (g << 11) + ((wcn + (q << 4) + l16) << 3)) ^ (g << 4)]; \
      acc[q] = __builtin_amdgcn_mfma_f32_16x16x32_bf16(a.v, b.v, acc[q], 0, 0, 0); \
    } \
  }

#define RUN_LAYER(wp, T) do { \
  const u16* pb = (wp) + ((size_t)tid << 3); \
  uint4 p0 = *(const uint4*)(pb); \
  uint4 p1 = *(const uint4*)(pb + 8192); \
  _Pragma("unroll 1") \
  for (int t = 0; t < (T); ++t) { \
    __syncthreads(); \
    WRBT(tid, p0); WRBT(tid + 1024, p1); \
    __syncthreads(); \
    if (t + 1 < (T)) {                     /* issued under MFMA phase */ \
      const u16* nb = pb + ((size_t)(t + 1) << 14); \
      p0 = *(const uint4*)nb; p1 = *(const uint4*)(nb + 8192); \
    } \
    MFMA_STEP(t) \
  } \
} while (0)

#define LN_STATS() do { \
  _Pragma("unroll") \
  for (int r = 0; r < 4; ++r) { \
    float s  = acc[0][r] + acc[1][r] + acc[2][r] + acc[3][r]; \
    float s2 = acc[0][r]*acc[0][r] + acc[1][r]*acc[1][r] + acc[2][r]*acc[2][r] + acc[3][r]*acc[3][r]; \
    s  += __shfl_xor(s, 1);  s  += __shfl_xor(s, 2);  s  += __shfl_xor(s, 4);  s  += __shfl_xor(s, 8); \
    s2 += __shfl_xor(s2, 1); s2 += __shfl_xor(s2, 2); s2 += __shfl_xor(s2, 4); s2 += __shfl_xor(s2, 8); \
    if (l16 == 0) { int m = wr16 + g4 + r; red[m][wc2] = s; red[m][wc2 + 1] = s2; } \
  } \
  __syncthreads(); \
  if (tid < 64) { \
    float s  = red[tid][0] + red[tid][2] + red[tid][4] + red[tid][6]; \
    float s2 = red[tid][1] + red[tid][3] + red[tid][5] + red[tid][7]; \
    float mu  = s * (1.f / 256.f); \
    float var = s2 * (1.f / 256.f) - mu * mu; \
    murs[tid][0] = mu; murs[tid][1] = rsqrtf(var + 1e-6f); \
  } \
  __syncthreads(); \
} while (0)

__global__ __launch_bounds__(1024)
void k_fused(
    const u16* __restrict__ X, const float* __restrict__ nodes,
    const u16* __restrict__ wm, const u16* __restrict__ w0,
    const u16* __restrict__ w1, const u16* __restrict__ w2,
    const float* __restrict__ b0, const float* __restrict__ b1,
    const float* __restrict__ b2,
    const float* __restrict__ lnAs, const float* __restrict__ lnAb,
    const float* __restrict__ lnOs, const float* __restrict__ lnOb,
    float* __restrict__ out)
{
  __shared__ u16 At[64 * 320];     // XOR-swizzled: byte ^= (row&7)<<4
  __shared__ u16 Bt[16384];        // K=64 step: [kk][g][n][j] ^ (g<<4) u16-swz
  __shared__ float red[64][8];
  __shared__ float murs[64][2];

  const int tid = threadIdx.x;
  const int lane = tid & 63;
  const int w16 = tid >> 6;              // 0..15
  const int wr16 = (w16 >> 2) << 4;      // row base within tile (0,16,32,48)
  const int wcn = (w16 & 3) << 6;        // col base (0,64,128,192)
  const int wc2 = (w16 & 3) << 1;
  const int l16 = lane & 15, g = lane >> 4, g4 = g << 2;
  const int r0 = blockIdx.x * 64;

  char* const atb = (char*)At;

  // ---- stage X (bf16, K=320) into swizzled At ----
  #pragma unroll
  for (int it = 0; it < 3; ++it) {
    int c = tid + it * 1024;             // 2560 chunks of 16B
    if (c < 2560) {
      int r = c / 40, seg = c - r * 40;
      int row = r0 + r;
      uint4 v = {0u, 0u, 0u, 0u};
      if (row < NN) v = *(const uint4*)(X + (size_t)row * 320 + seg * 8);
      *(uint4*)(atb + ((r * 640 + seg * 16) ^ ((r & 7) << 4))) = v;
    }
  }

  f32x4 acc[4];
  const f32x4 z = {0.f, 0.f, 0.f, 0.f};
  #pragma unroll
  for (int q = 0; q < 4; ++q) acc[q] = z;

  // ---- GEMM: X @ Wmsg (K=320, 5 steps; first barrier fences staging) ----
  RUN_LAYER(wm, 5);

  // ---- aggr epilogue: v = relu(acc) + nodes ----
  #pragma unroll
  for (int q = 0; q < 4; ++q) {
    int n = wcn + (q << 4) + l16;
    #pragma unroll
    for (int r = 0; r < 4; ++r) {
      int row = r0 + wr16 + g4 + r;
      float nv = (row < NN) ? nodes[(size_t)row * 256 + n] : 0.f;
      acc[q][r] = fmaxf(acc[q][r], 0.f) + nv;
    }
  }
  LN_STATS();                            // barrier inside also fences At reads
  // h = LN_a(v) -> bf16 into At (residual + next A operand)
  #pragma unroll
  for (int q = 0; q < 4; ++q) {
    int n = wcn + (q << 4) + l16;
    float scl = lnAs[n], bia = lnAb[n];
    #pragma unroll
    for (int r = 0; r < 4; ++r) {
      int m = wr16 + g4 + r;
      float h = (acc[q][r] - murs[m][0]) * murs[m][1] * scl + bia;
      *(u16*)AT_ADDR(m, n) = f2bfu(h);
      acc[q][r] = 0.f;
    }
  }

  // ---- 3 MLP layers; residual lives in At (bf16) ----
  #pragma unroll 1
  for (int l = 0; l < 3; ++l) {
    const u16* wp = (l == 0) ? w0 : (l == 1) ? w1 : w2;
    RUN_LAYER(wp, 4);
    __syncthreads();                     // all At MFMA reads done

    if (l < 2) {
      const float* bp = (l == 0) ? b0 : b1;
      #pragma unroll
      for (int q = 0; q < 4; ++q) {
        int n = wcn + (q << 4) + l16;
        float bn = bp[n];
        #pragma unroll
        for (int r = 0; r < 4; ++r) {
          int m = wr16 + g4 + r;
          u16* p = (u16*)AT_ADDR(m, n);
          float xn = bf2f(*p) + fmaxf(acc[q][r] + bn, 0.f);
          *p = f2bfu(xn);                // owner-thread RMW (disjoint)
          acc[q][r] = 0.f;
        }
      }
    } else {
      // final: acc = nodes + x + acc + b2   (At read-only here)
      #pragma unroll
      for (int q = 0; q < 4; ++q) {
        int n = wcn + (q << 4) + l16;
        float bn = b2[n];
        #pragma unroll
        for (int r = 0; r < 4; ++r) {
          int m = wr16 + g4 + r;
          int row = r0 + m;
          float nv = (row < NN) ? nodes[(size_t)row * 256 + n] : 0.f;
          acc[q][r] = nv + bf2f(*(const u16*)AT_ADDR(m, n)) + acc[q][r] + bn;
        }
      }
    }
  }

  // ---- final LayerNorm ----
  LN_STATS();
  #pragma unroll
  for (int q = 0; q < 4; ++q) {
    int n = wcn + (q << 4) + l16;
    float scl = lnOs[n], bia = lnOb[n];
    #pragma unroll
    for (int r = 0; r < 4; ++r) {
      int m = wr16 + g4 + r;
      int row = r0 + m;
      if (row < NN)
        out[(size_t)row * 256 + n] =
            (acc[q][r] - murs[m][0]) * murs[m][1] * scl + bia;
    }
  }
}

// ---------------------------------------------------------------------------
extern "C" void kernel_launch(void* const* d_in, const int* in_sizes, int n_in,
                              void* d_out, int out_size, void* d_ws, size_t ws_size,
                              hipStream_t stream)
{
  const float* nodes = (const float*)d_in[0];
  const float* edges = (const float*)d_in[1];
  const int* senders = (const int*)d_in[2];
  const int* receivers = (const int*)d_in[3];
  const float* Wmsg = (const float*)d_in[4];
  const float* W0 = (const float*)d_in[5];
  const float* b0 = (const float*)d_in[6];
  const float* W1 = (const float*)d_in[7];
  const float* b1 = (const float*)d_in[8];
  const float* W2 = (const float*)d_in[9];
  const float* b2 = (const float*)d_in[10];
  const float* lnAs = (const float*)d_in[11];
  const float* lnAb = (const float*)d_in[12];
  const float* lnOs = (const float*)d_in[13];
  const float* lnOb = (const float*)d_in[14];
  float* out = (float*)d_out;
  (void)in_sizes; (void)n_in; (void)out_size; (void)ws_size;

  char* w = (char*)d_ws;
  size_t off = 0;
  auto take = [&](size_t b) { void* p = w + off; off += (b + 511) & ~(size_t)511; return p; };

  u16*   nodes_bf = (u16*)take((size_t)NN * 256 * 2);
  u16*   wmsg_p   = (u16*)take(320 * 256 * 2);
  u16*   w0_p     = (u16*)take(256 * 256 * 2);
  u16*   w1_p     = (u16*)take(256 * 256 * 2);
  u16*   w2_p     = (u16*)take(256 * 256 * 2);
  u16*   X        = (u16*)take((size_t)NN * 320 * 2);
  int*   cnt      = (int*)take((size_t)NN * 4);
  int*   loc      = (int*)take((size_t)NN * 4);
  int*   offs     = (int*)take((size_t)(NN + 1) * 4);
  int*   cursor   = (int*)take((size_t)NN * 4);
  int*   s_snd    = (int*)take((size_t)NE * 4);
  int*   s_eid    = (int*)take((size_t)NE * 4);
  int*   bsum     = (int*)take(256 * 4);
  int*   bpre     = (int*)take(256 * 4);

  const int NB = (NN + 255) / 256;  // 196

  hipMemsetAsync(cnt, 0, (size_t)NN * 4, stream);
  k_prep<<<NB_CVT + NB_PACK + NB_HIST, 256, 0, stream>>>(
      nodes, nodes_bf, Wmsg, W0, W1, W2, wmsg_p, w0_p, w1_p, w2_p,
      receivers, cnt);

  k_scan1<<<NB, 256, 0, stream>>>(cnt, loc, bsum);
  k_scan2<<<1, 256, 0, stream>>>(bsum, bpre, NB);
  k_scan3<<<NB, 256, 0, stream>>>(loc, bpre, offs, cursor);
  k_scatter<<<(NE + 255) / 256, 256, 0, stream>>>(senders, receivers, cursor, s_snd, s_eid);

  k_aggr<<<NN / 16, 256, 0, stream>>>(nodes_bf, edges, offs, s_snd, s_eid, X);

  const int MB = (NN + 63) / 64;    // 782
  k_fused<<<MB, 1024, 0, stream>>>(X, nodes, wmsg_p, w0_p, w1_p, w2_p,
                                   b0, b1, b2, lnAs, lnAb, lnOs, lnOb, out);
}

// Round 11
// 225.699 us; speedup vs baseline: 1.1006x; 1.1006x over previous
//
#include <hip/hip_runtime.h>

#define NN 50000
#define NE 400000

typedef unsigned short u16;
typedef unsigned int   u32;
typedef __bf16 bf16x4 __attribute__((ext_vector_type(4)));
typedef __bf16 bf16x8 __attribute__((ext_vector_type(8)));
typedef float  f32x4  __attribute__((ext_vector_type(4)));

union ABFrag { bf16x8 v; bf16x4 h[2]; };
union BFrag  { uint4 u; bf16x8 v; };

__device__ __forceinline__ u16 f2bfu(float f) {
  u32 u = __builtin_bit_cast(u32, f);
  return (u16)((u + 0x7FFFu + ((u >> 16) & 1u)) >> 16);  // RNE f32->bf16
}
__device__ __forceinline__ float bf2f(u16 u) {
  return __builtin_bit_cast(float, (u32)u << 16);
}

// ---------------- prep: cvt + weight-pack + hist in ONE launch ---------------
// pack[((t*256+n)*4+g)*8+j] = W[32t + 4g + (j%4) + 16*(j/4)][n]
__device__ __forceinline__ void pack_one(const float* __restrict__ W,
                                         u16* __restrict__ P, int idx) {
  int k = idx >> 8, n = idx & 255;
  int t = k >> 5, kp = k & 31;
  int g = (kp & 15) >> 2;
  int j = (kp & 3) | ((kp >> 4) << 2);
  P[(((t << 8) + n) << 5) + (g << 3) + j] = f2bfu(W[idx]);
}

#define NB_CVT  12500      // NN*256/4 / 256
#define NB_PACK 1088       // (320*256 + 3*256*256) / 256
#define NB_HIST 1563       // ceil(NE/256)

__global__ __launch_bounds__(256) void k_prep(
    const float* __restrict__ nodes, u16* __restrict__ nodes_bf,
    const float* __restrict__ Wm, const float* __restrict__ W0,
    const float* __restrict__ W1, const float* __restrict__ W2,
    u16* __restrict__ Pm, u16* __restrict__ P0,
    u16* __restrict__ P1, u16* __restrict__ P2,
    const int* __restrict__ recv, int* __restrict__ cnt)
{
  int b = blockIdx.x, t = threadIdx.x;
  if (b < NB_CVT) {
    int i = b * 256 + t;                         // exact: 12500*256 = NN*64
    float4 f = ((const float4*)nodes)[i];
    ushort4 o;
    o.x = f2bfu(f.x); o.y = f2bfu(f.y); o.z = f2bfu(f.z); o.w = f2bfu(f.w);
    ((ushort4*)nodes_bf)[i] = o;
  } else if (b < NB_CVT + NB_PACK) {
    int idx = (b - NB_CVT) * 256 + t;
    const int S0 = 320 * 256, S1 = S0 + 65536, S2 = S1 + 65536;
    if (idx < S0)      pack_one(Wm, Pm, idx);
    else if (idx < S1) pack_one(W0, P0, idx - S0);
    else if (idx < S2) pack_one(W1, P1, idx - S1);
    else               pack_one(W2, P2, idx - S2);
  } else {
    int i = (b - NB_CVT - NB_PACK) * 256 + t;
    if (i < NE) atomicAdd(&cnt[recv[i]], 1);
  }
}

// ---------------- counting-sort scan + scatter -------------------------------
__global__ __launch_bounds__(256) void k_scan1(const int* __restrict__ cnt,
                                               int* __restrict__ loc,
                                               int* __restrict__ bsum) {
  __shared__ int sm[256];
  int t = threadIdx.x, i = blockIdx.x * 256 + t;
  int v = (i < NN) ? cnt[i] : 0;
  sm[t] = v;
  __syncthreads();
  #pragma unroll
  for (int d = 1; d < 256; d <<= 1) {
    int x = sm[t];
    int y = (t >= d) ? sm[t - d] : 0;
    __syncthreads();
    sm[t] = x + y;
    __syncthreads();
  }
  if (i < NN) loc[i] = sm[t] - v;
  if (t == 255) bsum[blockIdx.x] = sm[255];
}

__global__ __launch_bounds__(256) void k_scan2(int* __restrict__ bsum,
                                               int* __restrict__ bpre, int nb) {
  __shared__ int sm[256];
  int t = threadIdx.x;
  int v = (t < nb) ? bsum[t] : 0;
  sm[t] = v;
  __syncthreads();
  #pragma unroll
  for (int d = 1; d < 256; d <<= 1) {
    int x = sm[t];
    int y = (t >= d) ? sm[t - d] : 0;
    __syncthreads();
    sm[t] = x + y;
    __syncthreads();
  }
  if (t < nb) bpre[t] = sm[t] - v;
}

__global__ __launch_bounds__(256) void k_scan3(const int* __restrict__ loc,
                                               const int* __restrict__ bpre,
                                               int* __restrict__ offs,
                                               int* __restrict__ cursor) {
  int i = blockIdx.x * 256 + threadIdx.x;
  if (i < NN) {
    int o = loc[i] + bpre[blockIdx.x];
    offs[i] = o;
    cursor[i] = o;
  }
  if (i == NN - 1) offs[NN] = NE;
}

__global__ __launch_bounds__(256) void k_scatter(
    const int* __restrict__ snd, const int* __restrict__ recv,
    int* __restrict__ cursor, int2* __restrict__ s_pair) {
  int e = blockIdx.x * 256 + threadIdx.x;
  if (e < NE) {
    int p = atomicAdd(&cursor[recv[e]], 1);
    int2 pr; pr.x = snd[e]; pr.y = e;
    s_pair[p] = pr;
  }
}

// ---------------- aggregation: index-broadcast volleys -----------------------
// One wave per node. Per volley of 8 edges: ONE 8B/lane load fetches 8 packed
// (sender,eid) pairs; 16 compile-time __shfl broadcasts put them in SGPRs;
// then 16 fully INDEPENDENT loads (8 node-row gathers + 8 edge rows) are in
// flight at once. Dependent chain per 8 edges: ~2 latencies, not ~8-16.
// Loads are unconditional (clamped index); accumulation predicated on rem>k.
__global__ __launch_bounds__(256) void k_aggr(
    const u16* __restrict__ nodes_bf, const float* __restrict__ edges,
    const int* __restrict__ offs, const int2* __restrict__ s_pair,
    u16* __restrict__ X)
{
  const int node = blockIdx.x * 4 + (threadIdx.x >> 6);  // grid exact: NN/4
  const int lane = threadIdx.x & 63;
  const int beg = offs[node], end = offs[node + 1];
  float a0 = 0.f, a1 = 0.f, a2 = 0.f, a3 = 0.f, a4 = 0.f;

  for (int jb = beg; jb < end; jb += 8) {
    int j = jb + (lane & 7);
    if (j >= end) j = end - 1;          // clamp: loop body implies end > beg
    int2 pr = s_pair[j];                // one dwordx2; lanes 8+ duplicate 0-7
    const int rem = end - jb;

#define GATHER(K) \
    int s##K = __shfl(pr.x, K); int e##K = __shfl(pr.y, K); \
    ushort4 n##K = *(const ushort4*)(nodes_bf + (size_t)s##K * 256 + (lane << 2)); \
    float v##K = edges[(size_t)e##K * 64 + lane];

    GATHER(0) GATHER(1) GATHER(2) GATHER(3)
    GATHER(4) GATHER(5) GATHER(6) GATHER(7)
#undef GATHER

#define ACCUM(K) \
    if (rem > K) { \
      a0 += bf2f(n##K.x); a1 += bf2f(n##K.y); \
      a2 += bf2f(n##K.z); a3 += bf2f(n##K.w); \
      a4 += v##K; }

    ACCUM(0) ACCUM(1) ACCUM(2) ACCUM(3)
    ACCUM(4) ACCUM(5) ACCUM(6) ACCUM(7)
#undef ACCUM
  }

  u16* xr = X + (size_t)node * 320;
  ushort4 o;
  o.x = f2bfu(a0); o.y = f2bfu(a1); o.z = f2bfu(a2); o.w = f2bfu(a3);
  *(ushort4*)(xr + (lane << 2)) = o;
  xr[256 + lane] = f2bfu(a4);
}

// ---------------- fully fused dense chain (unchanged from R10) ---------------
#define AT_ADDR(r, c) (atb + ((((r) * 640) + ((c) * 2)) ^ (((r) & 7) << 4)))

#define WRBT(c, v) do { int _c = (c); \
  int _i = (((_c >> 10) << 13) + ((_c & 3) << 11) + (((_c & 1023) >> 2) << 3)) ^ ((_c & 3) << 4); \
  *(uint4*)&Bt[_i] = (v); } while (0)

#define MFMA_STEP(t) \
  _Pragma("unroll") \
  for (int kk = 0; kk < 2; ++kk) { \
    ABFrag a; \
    const int kc = (((t) * 2 + kk) << 5) + (g << 2); \
    const int m = wr16 + l16; \
    a.h[0] = *(const bf16x4*)AT_ADDR(m, kc); \
    a.h[1] = *(const bf16x4*)AT_ADDR(m, kc + 16); \
    _Pragma("unroll") \
    for (int q = 0; q < 4; ++q) { \
      BFrag b; \
      b.u = *(const uint4*)&Bt[((kk << 13) + (g << 11) + ((wcn + (q << 4) + l16) << 3)) ^ (g << 4)]; \
      acc[q] = __builtin_amdgcn_mfma_f32_16x16x32_bf16(a.v, b.v, acc[q], 0, 0, 0); \
    } \
  }

#define RUN_LAYER(wp, T) do { \
  const u16* pb = (wp) + ((size_t)tid << 3); \
  uint4 p0 = *(const uint4*)(pb); \
  uint4 p1 = *(const uint4*)(pb + 8192); \
  _Pragma("unroll 1") \
  for (int t = 0; t < (T); ++t) { \
    __syncthreads(); \
    WRBT(tid, p0); WRBT(tid + 1024, p1); \
    __syncthreads(); \
    if (t + 1 < (T)) { \
      const u16* nb = pb + ((size_t)(t + 1) << 14); \
      p0 = *(const uint4*)nb; p1 = *(const uint4*)(nb + 8192); \
    } \
    MFMA_STEP(t) \
  } \
} while (0)

#define LN_STATS() do { \
  _Pragma("unroll") \
  for (int r = 0; r < 4; ++r) { \
    float s  = acc[0][r] + acc[1][r] + acc[2][r] + acc[3][r]; \
    float s2 = acc[0][r]*acc[0][r] + acc[1][r]*acc[1][r] + acc[2][r]*acc[2][r] + acc[3][r]*acc[3][r]; \
    s  += __shfl_xor(s, 1);  s  += __shfl_xor(s, 2);  s  += __shfl_xor(s, 4);  s  += __shfl_xor(s, 8); \
    s2 += __shfl_xor(s2, 1); s2 += __shfl_xor(s2, 2); s2 += __shfl_xor(s2, 4); s2 += __shfl_xor(s2, 8); \
    if (l16 == 0) { int m = wr16 + g4 + r; red[m][wc2] = s; red[m][wc2 + 1] = s2; } \
  } \
  __syncthreads(); \
  if (tid < 64) { \
    float s  = red[tid][0] + red[tid][2] + red[tid][4] + red[tid][6]; \
    float s2 = red[tid][1] + red[tid][3] + red[tid][5] + red[tid][7]; \
    float mu  = s * (1.f / 256.f); \
    float var = s2 * (1.f / 256.f) - mu * mu; \
    murs[tid][0] = mu; murs[tid][1] = rsqrtf(var + 1e-6f); \
  } \
  __syncthreads(); \
} while (0)

__global__ __launch_bounds__(1024)
void k_fused(
    const u16* __restrict__ X, const float* __restrict__ nodes,
    const u16* __restrict__ wm, const u16* __restrict__ w0,
    const u16* __restrict__ w1, const u16* __restrict__ w2,
    const float* __restrict__ b0, const float* __restrict__ b1,
    const float* __restrict__ b2,
    const float* __restrict__ lnAs, const float* __restrict__ lnAb,
    const float* __restrict__ lnOs, const float* __restrict__ lnOb,
    float* __restrict__ out)
{
  __shared__ u16 At[64 * 320];     // XOR-swizzled: byte ^= (row&7)<<4
  __shared__ u16 Bt[16384];        // K=64 step: [kk][g][n][j] ^ (g<<4) u16-swz
  __shared__ float red[64][8];
  __shared__ float murs[64][2];

  const int tid = threadIdx.x;
  const int lane = tid & 63;
  const int w16 = tid >> 6;              // 0..15
  const int wr16 = (w16 >> 2) << 4;      // row base within tile (0,16,32,48)
  const int wcn = (w16 & 3) << 6;        // col base (0,64,128,192)
  const int wc2 = (w16 & 3) << 1;
  const int l16 = lane & 15, g = lane >> 4, g4 = g << 2;
  const int r0 = blockIdx.x * 64;

  char* const atb = (char*)At;

  // ---- stage X (bf16, K=320) into swizzled At ----
  #pragma unroll
  for (int it = 0; it < 3; ++it) {
    int c = tid + it * 1024;             // 2560 chunks of 16B
    if (c < 2560) {
      int r = c / 40, seg = c - r * 40;
      int row = r0 + r;
      uint4 v = {0u, 0u, 0u, 0u};
      if (row < NN) v = *(const uint4*)(X + (size_t)row * 320 + seg * 8);
      *(uint4*)(atb + ((r * 640 + seg * 16) ^ ((r & 7) << 4))) = v;
    }
  }

  f32x4 acc[4];
  const f32x4 z = {0.f, 0.f, 0.f, 0.f};
  #pragma unroll
  for (int q = 0; q < 4; ++q) acc[q] = z;

  // ---- GEMM: X @ Wmsg (K=320, 5 steps; first barrier fences staging) ----
  RUN_LAYER(wm, 5);

  // ---- aggr epilogue: v = relu(acc) + nodes ----
  #pragma unroll
  for (int q = 0; q < 4; ++q) {
    int n = wcn + (q << 4) + l16;
    #pragma unroll
    for (int r = 0; r < 4; ++r) {
      int row = r0 + wr16 + g4 + r;
      float nv = (row < NN) ? nodes[(size_t)row * 256 + n] : 0.f;
      acc[q][r] = fmaxf(acc[q][r], 0.f) + nv;
    }
  }
  LN_STATS();                            // barrier inside also fences At reads
  // h = LN_a(v) -> bf16 into At (residual + next A operand)
  #pragma unroll
  for (int q = 0; q < 4; ++q) {
    int n = wcn + (q << 4) + l16;
    float scl = lnAs[n], bia = lnAb[n];
    #pragma unroll
    for (int r = 0; r < 4; ++r) {
      int m = wr16 + g4 + r;
      float h = (acc[q][r] - murs[m][0]) * murs[m][1] * scl + bia;
      *(u16*)AT_ADDR(m, n) = f2bfu(h);
      acc[q][r] = 0.f;
    }
  }

  // ---- 3 MLP layers; residual lives in At (bf16) ----
  #pragma unroll 1
  for (int l = 0; l < 3; ++l) {
    const u16* wp = (l == 0) ? w0 : (l == 1) ? w1 : w2;
    RUN_LAYER(wp, 4);
    __syncthreads();                     // all At MFMA reads done

    if (l < 2) {
      const float* bp = (l == 0) ? b0 : b1;
      #pragma unroll
      for (int q = 0; q < 4; ++q) {
        int n = wcn + (q << 4) + l16;
        float bn = bp[n];
        #pragma unroll
        for (int r = 0; r < 4; ++r) {
          int m = wr16 + g4 + r;
          u16* p = (u16*)AT_ADDR(m, n);
          float xn = bf2f(*p) + fmaxf(acc[q][r] + bn, 0.f);
          *p = f2bfu(xn);                // owner-thread RMW (disjoint)
          acc[q][r] = 0.f;
        }
      }
    } else {
      // final: acc = nodes + x + acc + b2   (At read-only here)
      #pragma unroll
      for (int q = 0; q < 4; ++q) {
        int n = wcn + (q << 4) + l16;
        float bn = b2[n];
        #pragma unroll
        for (int r = 0; r < 4; ++r) {
          int m = wr16 + g4 + r;
          int row = r0 + m;
          float nv = (row < NN) ? nodes[(size_t)row * 256 + n] : 0.f;
          acc[q][r] = nv + bf2f(*(const u16*)AT_ADDR(m, n)) + acc[q][r] + bn;
        }
      }
    }
  }

  // ---- final LayerNorm ----
  LN_STATS();
  #pragma unroll
  for (int q = 0; q < 4; ++q) {
    int n = wcn + (q << 4) + l16;
    float scl = lnOs[n], bia = lnOb[n];
    #pragma unroll
    for (int r = 0; r < 4; ++r) {
      int m = wr16 + g4 + r;
      int row = r0 + m;
      if (row < NN)
        out[(size_t)row * 256 + n] =
            (acc[q][r] - murs[m][0]) * murs[m][1] * scl + bia;
    }
  }
}

// ---------------------------------------------------------------------------
extern "C" void kernel_launch(void* const* d_in, const int* in_sizes, int n_in,
                              void* d_out, int out_size, void* d_ws, size_t ws_size,
                              hipStream_t stream)
{
  const float* nodes = (const float*)d_in[0];
  const float* edges = (const float*)d_in[1];
  const int* senders = (const int*)d_in[2];
  const int* receivers = (const int*)d_in[3];
  const float* Wmsg = (const float*)d_in[4];
  const float* W0 = (const float*)d_in[5];
  const float* b0 = (const float*)d_in[6];
  const float* W1 = (const float*)d_in[7];
  const float* b1 = (const float*)d_in[8];
  const float* W2 = (const float*)d_in[9];
  const float* b2 = (const float*)d_in[10];
  const float* lnAs = (const float*)d_in[11];
  const float* lnAb = (const float*)d_in[12];
  const float* lnOs = (const float*)d_in[13];
  const float* lnOb = (const float*)d_in[14];
  float* out = (float*)d_out;
  (void)in_sizes; (void)n_in; (void)out_size; (void)ws_size;

  char* w = (char*)d_ws;
  size_t off = 0;
  auto take = [&](size_t b) { void* p = w + off; off += (b + 511) & ~(size_t)511; return p; };

  u16*   nodes_bf = (u16*)take((size_t)NN * 256 * 2);
  u16*   wmsg_p   = (u16*)take(320 * 256 * 2);
  u16*   w0_p     = (u16*)take(256 * 256 * 2);
  u16*   w1_p     = (u16*)take(256 * 256 * 2);
  u16*   w2_p     = (u16*)take(256 * 256 * 2);
  u16*   X        = (u16*)take((size_t)NN * 320 * 2);
  int*   cnt      = (int*)take((size_t)NN * 4);
  int*   loc      = (int*)take((size_t)NN * 4);
  int*   offs     = (int*)take((size_t)(NN + 1) * 4);
  int*   cursor   = (int*)take((size_t)NN * 4);
  int2*  s_pair   = (int2*)take((size_t)NE * 8);
  int*   bsum     = (int*)take(256 * 4);
  int*   bpre     = (int*)take(256 * 4);

  const int NB = (NN + 255) / 256;  // 196

  hipMemsetAsync(cnt, 0, (size_t)NN * 4, stream);
  k_prep<<<NB_CVT + NB_PACK + NB_HIST, 256, 0, stream>>>(
      nodes, nodes_bf, Wmsg, W0, W1, W2, wmsg_p, w0_p, w1_p, w2_p,
      receivers, cnt);

  k_scan1<<<NB, 256, 0, stream>>>(cnt, loc, bsum);
  k_scan2<<<1, 256, 0, stream>>>(bsum, bpre, NB);
  k_scan3<<<NB, 256, 0, stream>>>(loc, bpre, offs, cursor);
  k_scatter<<<(NE + 255) / 256, 256, 0, stream>>>(senders, receivers, cursor, s_pair);

  k_aggr<<<NN / 4, 256, 0, stream>>>(nodes_bf, edges, offs, s_pair, X);

  const int MB = (NN + 63) / 64;    // 782
  k_fused<<<MB, 1024, 0, stream>>>(X, nodes, wmsg_p, w0_p, w1_p, w2_p,
                                   b0, b1, b2, lnAs, lnAb, lnOs, lnOb, out);
}